// Round 3
// baseline (5257.425 us; speedup 1.0000x reference)
//
#include <hip/hip_runtime.h>

typedef unsigned short u16;

__device__ __forceinline__ float bf2f(u16 u) {
    return __uint_as_float(((unsigned int)u) << 16);
}

#define T_LEN 32768

struct LdBF16 {
    static __device__ __forceinline__ float ld(const void* p, int i) {
        return bf2f(((const u16*)p)[i]);
    }
};
struct LdF32 {
    static __device__ __forceinline__ float ld(const void* p, int i) {
        return ((const float*)p)[i];
    }
};

// One wave (64 lanes) per batch sample. Lane g in [0,48) owns gate column g
// (g<16: reset, 16..31: input, 32..47: new). Lanes 32..47 additionally own
// state element h_{g-32}. Lanes 48..63 are spectators (compute duplicates).
template <typename LD>
__device__ __forceinline__ void gru_run(
    const void* x,     const void* c,    const void* h0,
    const void* w1,    const void* b1,   const void* w2,    const void* b2,
    const void* pihw,  const void* pihb, const void* phhw,  const void* phhb,
    const void* pbihw, const void* pbihb,const void* pbhhw, const void* pbhhb,
    const void* oww,   const void* owb,  float* out, int b, int ln, float* ybuf)
{
    // ---- hypernetwork: cond MLP -> a2[8] (uniform; computed redundantly per lane) ----
    float cv[8], a1[8], a2[8];
    #pragma unroll
    for (int n = 0; n < 8; ++n) cv[n] = LD::ld(c, b*8 + n);
    #pragma unroll
    for (int m = 0; m < 8; ++m) {
        float s = LD::ld(b1, m);
        #pragma unroll
        for (int n = 0; n < 8; ++n) s = fmaf(cv[n], LD::ld(w1, m*8 + n), s);
        a1[m] = (s >= 0.f) ? s : 0.1f * s;
    }
    #pragma unroll
    for (int m = 0; m < 8; ++m) {
        float s = LD::ld(b2, m);
        #pragma unroll
        for (int k = 0; k < 8; ++k) s = fmaf(a1[k], LD::ld(w2, m*8 + k), s);
        a2[m] = (s >= 0.f) ? s : 0.1f * s;
    }

    // ---- per-lane GRU weights from projections ----
    const int g = (ln < 48) ? ln : (ln - 48);   // spectators mirror a valid column
    float wih, bih, bhh, whh[16];
    {
        float s = LD::ld(pihb, g);
        #pragma unroll
        for (int m = 0; m < 8; ++m) s = fmaf(a2[m], LD::ld(pihw, g*8 + m), s);
        wih = s;
    }
    {
        float s = LD::ld(pbihb, g);
        #pragma unroll
        for (int m = 0; m < 8; ++m) s = fmaf(a2[m], LD::ld(pbihw, g*8 + m), s);
        bih = s;
    }
    {
        float s = LD::ld(pbhhb, g);
        #pragma unroll
        for (int m = 0; m < 8; ++m) s = fmaf(a2[m], LD::ld(pbhhw, g*8 + m), s);
        bhh = s;
    }
    #pragma unroll
    for (int r = 0; r < 16; ++r) {
        const int row = r*48 + g;               // w_hh[b, r, g] row-major stride 48
        float s = LD::ld(phhb, row);
        #pragma unroll
        for (int m = 0; m < 8; ++m) s = fmaf(a2[m], LD::ld(phhw, row*8 + m), s);
        whh[r] = s;
    }

    const float owv = LD::ld(oww, ln & 15);
    const float obv = LD::ld(owb, 0);

    // state: hl per-lane (meaningful in lanes 32..47), hs[] wave-uniform (SGPRs)
    float hl = LD::ld(h0, b*16 + (ln & 15));
    float hs[16];
    #pragma unroll
    for (int j = 0; j < 16; ++j)
        hs[j] = __int_as_float(__builtin_amdgcn_readlane(__float_as_int(hl), 32 + j));

    const int addr1 = (ln & 15) * 4;   // bpermute: fetch resetgate_j (lanes 0..15)
    const int addr2 = addr1 + 64;      // bpermute: fetch inputgate_j (lanes 16..31)
    const int xbase = b * T_LEN;
    float* yb = out + b * T_LEN;

    float xcur = LD::ld(x, xbase + ln);  // 64 timesteps of x per chunk, one per lane
    for (int t0 = 0; t0 < T_LEN; t0 += 64) {
        const int tn = t0 + 64;
        const float xnxt = LD::ld(x, xbase + ((tn < T_LEN) ? tn : 0) + ln);  // prefetch

        #pragma unroll 8
        for (int tt = 0; tt < 64; ++tt) {
            const float xt = __int_as_float(__builtin_amdgcn_readlane(__float_as_int(xcur), tt));
            const float ip = fmaf(xt, wih, bih);
            // hh[g] = sum_r h[r]*whh[r][g] + bhh[g], 4 independent FMA chains
            float acc0 = fmaf(hs[0], whh[0], bhh);
            float acc1 = hs[1] * whh[1];
            float acc2 = hs[2] * whh[2];
            float acc3 = hs[3] * whh[3];
            #pragma unroll
            for (int r = 4; r < 16; r += 4) {
                acc0 = fmaf(hs[r+0], whh[r+0], acc0);
                acc1 = fmaf(hs[r+1], whh[r+1], acc1);
                acc2 = fmaf(hs[r+2], whh[r+2], acc2);
                acc3 = fmaf(hs[r+3], whh[r+3], acc3);
            }
            const float acc = (acc0 + acc1) + (acc2 + acc3);
            const float z  = ip + acc;
            // sigmoid(z) = 1/(1+2^(-z*log2e))   (valid on lanes 0..31)
            const float sg = __builtin_amdgcn_rcpf(1.f + __builtin_amdgcn_exp2f(z * -1.44269504f));
            const float rq = __int_as_float(__builtin_amdgcn_ds_bpermute(addr1, __float_as_int(sg)));
            const float ig = __int_as_float(__builtin_amdgcn_ds_bpermute(addr2, __float_as_int(sg)));
            // newgate = tanh(ip + resetgate*acc)  (valid on lanes 32..47)
            const float zn = fmaf(rq, acc, ip);
            const float nn = fmaf(-2.f,
                __builtin_amdgcn_rcpf(1.f + __builtin_amdgcn_exp2f(zn * 2.88539008f)), 1.f);
            // h' = n + i*(h - n)
            hl = fmaf(ig, hl - nn, nn);
            #pragma unroll
            for (int j = 0; j < 16; ++j)
                hs[j] = __int_as_float(__builtin_amdgcn_readlane(__float_as_int(hl), 32 + j));
            if ((ln & 48) == 32) ybuf[tt*16 + (ln & 15)] = hl * owv;
        }
        __syncthreads();  // single wave: orders ybuf writes vs reads
        // y_t = ob + sum_j h_j*ow_j  — lane l reduces row l, coalesced f32 store
        const float4 u0 = *(const float4*)&ybuf[ln*16 + 0];
        const float4 u1 = *(const float4*)&ybuf[ln*16 + 4];
        const float4 u2 = *(const float4*)&ybuf[ln*16 + 8];
        const float4 u3 = *(const float4*)&ybuf[ln*16 + 12];
        const float s0 = (u0.x + u0.y) + (u0.z + u0.w);
        const float s1 = (u1.x + u1.y) + (u1.z + u1.w);
        const float s2 = (u2.x + u2.y) + (u2.z + u2.w);
        const float s3 = (u3.x + u3.y) + (u3.z + u3.w);
        yb[t0 + ln] = obv + ((s0 + s1) + (s2 + s3));
        xcur = xnxt;
    }

    // h_last: [B,1,R] appended after y (f32)
    if ((ln & 48) == 32)
        out[64 * T_LEN + b*16 + (ln & 15)] = hl;
}

__global__ __launch_bounds__(64, 1) void hyper_gru_kernel(
    const void* x,     const void* c,    const void* h0,
    const void* w1,    const void* b1,   const void* w2,    const void* b2,
    const void* pihw,  const void* pihb, const void* phhw,  const void* phhb,
    const void* pbihw, const void* pbihb,const void* pbhhw, const void* pbhhb,
    const void* oww,   const void* owb,  float* out)
{
    const int b  = blockIdx.x;
    const int ln = threadIdx.x;
    __shared__ float ybuf[1024];   // [64 timesteps][16 h-elements]

    // ---- runtime dtype detection on x ----
    // If x is f32, even u16 elements are mantissa low-halves (~uniform bits).
    // If x is bf16, every even u16 is bf16 of N(0,1): exponent field ~[117,129].
    const u16 probe = ((const u16*)x)[2 * ln];
    const int e = (probe >> 7) & 0xFF;
    const unsigned long long bal = __ballot(e < 100 || e > 140);
    const bool is_f32 = (__popcll(bal) > 8);

    if (is_f32)
        gru_run<LdF32>(x, c, h0, w1, b1, w2, b2, pihw, pihb, phhw, phhb,
                       pbihw, pbihb, pbhhw, pbhhb, oww, owb, out, b, ln, ybuf);
    else
        gru_run<LdBF16>(x, c, h0, w1, b1, w2, b2, pihw, pihb, phhw, phhb,
                        pbihw, pbihb, pbhhw, pbhhb, oww, owb, out, b, ln, ybuf);
}

extern "C" void kernel_launch(void* const* d_in, const int* in_sizes, int n_in,
                              void* d_out, int out_size, void* d_ws, size_t ws_size,
                              hipStream_t stream) {
    (void)in_sizes; (void)n_in; (void)d_ws; (void)ws_size; (void)out_size;
    hipLaunchKernelGGL(hyper_gru_kernel, dim3(64), dim3(64), 0, stream,
        (const void*)d_in[0],  (const void*)d_in[1],  (const void*)d_in[2],
        (const void*)d_in[3],  (const void*)d_in[4],  (const void*)d_in[5],  (const void*)d_in[6],
        (const void*)d_in[7],  (const void*)d_in[8],  (const void*)d_in[9],  (const void*)d_in[10],
        (const void*)d_in[11], (const void*)d_in[12], (const void*)d_in[13], (const void*)d_in[14],
        (const void*)d_in[15], (const void*)d_in[16],
        (float*)d_out);
}

// Round 4
// 4190.588 us; speedup vs baseline: 1.2546x; 1.2546x over previous
//
#include <hip/hip_runtime.h>

typedef unsigned short u16;

__device__ __forceinline__ float bf2f(u16 u) {
    return __uint_as_float(((unsigned int)u) << 16);
}

#define T_LEN 32768

struct LdBF16 {
    static __device__ __forceinline__ float ld(const void* p, int i) {
        return bf2f(((const u16*)p)[i]);
    }
};
struct LdF32 {
    static __device__ __forceinline__ float ld(const void* p, int i) {
        return ((const float*)p)[i];
    }
};

// quad_perm DPP move (VALU pipe, no LDS): lane reads quad-mate selected by CTRL
template <int CTRL>
__device__ __forceinline__ float qperm(float v) {
    return __int_as_float(__builtin_amdgcn_update_dpp(
        0, __float_as_int(v), CTRL, 0xF, 0xF, true));
}

// One wave per batch sample. lane = 4*j + q: quad j owns h-column j.
// q=0: reset gate, q=1: input gate, q=2: new gate, q=3: mirrors new gate.
// h is broadcast wave-uniform via v_readlane into SGPRs (one per h element),
// so every lane's 16-deep matvec uses uniform SGPR operands (legal).
// Gate handoffs (r -> n, i/n -> update) are intra-quad DPP broadcasts.
template <typename LD>
__device__ __forceinline__ void gru_run(
    const void* x,     const void* c,    const void* h0,
    const void* w1,    const void* b1,   const void* w2,    const void* b2,
    const void* pihw,  const void* pihb, const void* phhw,  const void* phhb,
    const void* pbihw, const void* pbihb,const void* pbhhw, const void* pbhhb,
    const void* oww,   const void* owb,  float* out, int b, int ln, float* ybuf)
{
    const int j = ln >> 2;
    const int q = ln & 3;
    const int gate = (q < 3) ? q : 2;

    // ---- hypernetwork: cond MLP -> a2[8] (uniform; redundant per lane) ----
    float cv[8], a1[8], a2[8];
    #pragma unroll
    for (int n = 0; n < 8; ++n) cv[n] = LD::ld(c, b*8 + n);
    #pragma unroll
    for (int m = 0; m < 8; ++m) {
        float s = LD::ld(b1, m);
        #pragma unroll
        for (int n = 0; n < 8; ++n) s = fmaf(cv[n], LD::ld(w1, m*8 + n), s);
        a1[m] = (s >= 0.f) ? s : 0.1f * s;
    }
    #pragma unroll
    for (int m = 0; m < 8; ++m) {
        float s = LD::ld(b2, m);
        #pragma unroll
        for (int k = 0; k < 8; ++k) s = fmaf(a1[k], LD::ld(w2, m*8 + k), s);
        a2[m] = (s >= 0.f) ? s : 0.1f * s;
    }

    // projection helper: row of (w @ P.T + pb)
    auto proj = [&](const void* W, const void* Bv, int row) {
        float s = LD::ld(Bv, row);
        #pragma unroll
        for (int m = 0; m < 8; ++m) s = fmaf(a2[m], LD::ld(W, row*8 + m), s);
        return s;
    };

    // Activation scales folded into weights at setup:
    //  r,i gates: acc = -log2e * z      -> sigmoid(z) = rcp(1+exp2(acc))
    //  n gate:    acc = -2log2e * (...) -> tanh = 2*rcp(1+exp2(acc)) - 1
    const float sc = (q < 2) ? -1.44269504f : -2.88539008f;
    const float sn = -2.88539008f;

    float W[16];                       // whh[:,gate*16+j], pre-scaled
    #pragma unroll
    for (int r = 0; r < 16; ++r)
        W[r] = sc * proj(phhw, phhb, r*48 + gate*16 + j);

    const int gih = gate*16 + j;
    float wihA, biasA;
    if (q < 2) {
        // r,i: fold x-weight + (b_ih + b_hh) into the accumulator init
        wihA  = sc * proj(pihw, pihb, gih);
        biasA = sc * (proj(pbihw, pbihb, gih) + proj(pbhhw, pbhhb, gih));
    } else {
        // n: b_hh_n must stay inside hh (it gets multiplied by resetgate)
        wihA  = 0.f;
        biasA = sc * proj(pbhhw, pbhhb, 32 + j);
    }
    // n-gate input projection, separate (NOT multiplied by resetgate)
    const float wihN = sn * proj(pihw, pihb, 32 + j);
    const float bihN = sn * proj(pbihw, pbihb, 32 + j);

    const float owv = LD::ld(oww, j);
    const float obv = LD::ld(owb, 0);

    // h_j replicated across quad j; SGPR broadcast copy hs[0..15]
    float hl = LD::ld(h0, b*16 + j);
    float hs[16];
    #pragma unroll
    for (int r = 0; r < 16; ++r)
        hs[r] = __int_as_float(__builtin_amdgcn_readlane(__float_as_int(hl), 4*r));

    const int xbase = b * T_LEN;
    float* yb = out + b * T_LEN;

    float xcur = LD::ld(x, xbase + ln);   // 64 timesteps per chunk, one per lane
    for (int t0 = 0; t0 < T_LEN; t0 += 64) {
        const int tn_ = t0 + 64;
        const float xnxt = LD::ld(x, xbase + ((tn_ < T_LEN) ? tn_ : 0) + ln);

        #pragma unroll 16
        for (int tt = 0; tt < 64; ++tt) {
            const float xt  = __int_as_float(__builtin_amdgcn_readlane(__float_as_int(xcur), tt));
            const float ipA = fmaf(xt, wihA, biasA);   // off critical path
            const float ipn = fmaf(xt, wihN, bihN);    // off critical path
            // acc = scaled (ip + bias + h.Whh) for r,i; scaled (b_hh_n + h.Whh_n) for n
            float a0 = fmaf(hs[0], W[0], ipA);
            float a1v = hs[1] * W[1];
            float a2v = hs[2] * W[2];
            float a3v = hs[3] * W[3];
            #pragma unroll
            for (int r = 4; r < 16; r += 4) {
                a0  = fmaf(hs[r+0], W[r+0], a0);
                a1v = fmaf(hs[r+1], W[r+1], a1v);
                a2v = fmaf(hs[r+2], W[r+2], a2v);
                a3v = fmaf(hs[r+3], W[r+3], a3v);
            }
            const float acc = (a0 + a1v) + (a2v + a3v);
            // q0 -> resetgate, q1 -> inputgate (q2/q3 compute harmless garbage)
            const float u  = __builtin_amdgcn_rcpf(1.f + __builtin_amdgcn_exp2f(acc));
            const float rg = qperm<0x00>(u);           // resetgate to whole quad
            const float tno = fmaf(rg, acc, ipn);      // q2: scaled (ip_n + r*hh_n)
            const float u2 = __builtin_amdgcn_rcpf(1.f + __builtin_amdgcn_exp2f(tno));
            const float nn = fmaf(2.f, u2, -1.f);      // tanh
            const float nb = qperm<0xAA>(nn);          // newgate from q2 to quad
            const float ig = qperm<0x55>(u);           // inputgate from q1 to quad
            hl = fmaf(ig, hl - nb, nb);                // h' = n + i*(h-n), replicated
            #pragma unroll
            for (int r = 0; r < 16; ++r)
                hs[r] = __int_as_float(__builtin_amdgcn_readlane(__float_as_int(hl), 4*r));
            if (q == 0) ybuf[tt*16 + j] = hl * owv;    // off critical path
        }
        __syncthreads();   // order ybuf writes vs reads (single wave)
        // y_t = ob + sum_j h_j*ow_j — lane l reduces row l, coalesced f32 store
        const float4 u0 = *(const float4*)&ybuf[ln*16 + 0];
        const float4 u1 = *(const float4*)&ybuf[ln*16 + 4];
        const float4 u2 = *(const float4*)&ybuf[ln*16 + 8];
        const float4 u3 = *(const float4*)&ybuf[ln*16 + 12];
        const float s0 = (u0.x + u0.y) + (u0.z + u0.w);
        const float s1 = (u1.x + u1.y) + (u1.z + u1.w);
        const float s2 = (u2.x + u2.y) + (u2.z + u2.w);
        const float s3 = (u3.x + u3.y) + (u3.z + u3.w);
        yb[t0 + ln] = obv + ((s0 + s1) + (s2 + s3));
        xcur = xnxt;
    }

    // h_last: [B,1,R] appended after y (f32)
    if (q == 0)
        out[64 * T_LEN + b*16 + j] = hl;
}

__global__ __launch_bounds__(64, 1) void hyper_gru_kernel(
    const void* x,     const void* c,    const void* h0,
    const void* w1,    const void* b1,   const void* w2,    const void* b2,
    const void* pihw,  const void* pihb, const void* phhw,  const void* phhb,
    const void* pbihw, const void* pbihb,const void* pbhhw, const void* pbhhb,
    const void* oww,   const void* owb,  float* out)
{
    const int b  = blockIdx.x;
    const int ln = threadIdx.x;
    __shared__ float ybuf[1024];   // [64 timesteps][16 h-elements]

    // ---- runtime dtype detection on x (f32 vs bf16) ----
    const u16 probe = ((const u16*)x)[2 * ln];
    const int e = (probe >> 7) & 0xFF;
    const unsigned long long bal = __ballot(e < 100 || e > 140);
    const bool is_f32 = (__popcll(bal) > 8);

    if (is_f32)
        gru_run<LdF32>(x, c, h0, w1, b1, w2, b2, pihw, pihb, phhw, phhb,
                       pbihw, pbihb, pbhhw, pbhhb, oww, owb, out, b, ln, ybuf);
    else
        gru_run<LdBF16>(x, c, h0, w1, b1, w2, b2, pihw, pihb, phhw, phhb,
                        pbihw, pbihb, pbhhw, pbhhb, oww, owb, out, b, ln, ybuf);
}

extern "C" void kernel_launch(void* const* d_in, const int* in_sizes, int n_in,
                              void* d_out, int out_size, void* d_ws, size_t ws_size,
                              hipStream_t stream) {
    (void)in_sizes; (void)n_in; (void)d_ws; (void)ws_size; (void)out_size;
    hipLaunchKernelGGL(hyper_gru_kernel, dim3(64), dim3(64), 0, stream,
        (const void*)d_in[0],  (const void*)d_in[1],  (const void*)d_in[2],
        (const void*)d_in[3],  (const void*)d_in[4],  (const void*)d_in[5],  (const void*)d_in[6],
        (const void*)d_in[7],  (const void*)d_in[8],  (const void*)d_in[9],  (const void*)d_in[10],
        (const void*)d_in[11], (const void*)d_in[12], (const void*)d_in[13], (const void*)d_in[14],
        (const void*)d_in[15], (const void*)d_in[16],
        (float*)d_out);
}